// Round 9
// baseline (318.981 us; speedup 1.0000x reference)
//
#include <hip/hip_runtime.h>

typedef __bf16 bf16;
typedef __bf16 bf16x4_t __attribute__((ext_vector_type(4)));
typedef __bf16 bf16x8_t __attribute__((ext_vector_type(8)));
typedef float f32x4_t __attribute__((ext_vector_type(4)));

#define MFMA16(a, b, c) __builtin_amdgcn_mfma_f32_16x16x32_bf16(a, b, c, 0, 0, 0)

// ---------------- fused: weight casts (blocks 0..4607) + conditional LN (4608..6655) ----------------
__global__ __launch_bounds__(256) void castln_k(const float* __restrict__ Wqkv,
                                                const float* __restrict__ Wout,
                                                const float* __restrict__ W1,
                                                bf16* __restrict__ wq,
                                                bf16* __restrict__ wo,
                                                bf16* __restrict__ w1b,
                                                const float* __restrict__ x,
                                                const int* __restrict__ gt,
                                                const float* __restrict__ tfg,
                                                const float* __restrict__ tfb,
                                                const float* __restrict__ tgg,
                                                const float* __restrict__ tgb,
                                                bf16* __restrict__ xn) {
    if (blockIdx.x < 4608) {
        int i = blockIdx.x * 256 + threadIdx.x;
        if (i < 786432) wq[i] = (bf16)Wqkv[i];
        else if (i < 1048576) wo[i - 786432] = (bf16)Wout[i - 786432];
        else if (i < 1179648) w1b[i - 1048576] = (bf16)W1[i - 1048576];
        return;
    }
    int wid = threadIdx.x >> 6, lane = threadIdx.x & 63;
    int t = (blockIdx.x - 4608) * 4 + wid;
    const float4* xr = (const float4*)(x + (size_t)t * 512);
    float4 a = xr[lane * 2], b = xr[lane * 2 + 1];
    float s = (a.x + a.y) + (a.z + a.w) + (b.x + b.y) + (b.z + b.w);
    float sq = a.x * a.x + a.y * a.y + a.z * a.z + a.w * a.w +
               b.x * b.x + b.y * b.y + b.z * b.z + b.w * b.w;
    for (int m = 1; m < 64; m <<= 1) {
        s += __shfl_xor(s, m, 64);
        sq += __shfl_xor(sq, m, 64);
    }
    float mean = s * (1.f / 512.f);
    float var = fmaxf(sq * (1.f / 512.f) - mean * mean, 0.f);
    float rstd = rsqrtf(var + 1e-5f);
    int g = gt[t];
    float4 o0, o1;
    if (g < 2) {
        const float4* gp = (const float4*)(g ? tgg : tfg);
        const float4* bp = (const float4*)(g ? tgb : tfb);
        float4 g0 = gp[lane * 2], g1 = gp[lane * 2 + 1];
        float4 b0 = bp[lane * 2], b1 = bp[lane * 2 + 1];
        o0.x = (a.x - mean) * rstd * g0.x + b0.x;
        o0.y = (a.y - mean) * rstd * g0.y + b0.y;
        o0.z = (a.z - mean) * rstd * g0.z + b0.z;
        o0.w = (a.w - mean) * rstd * g0.w + b0.w;
        o1.x = (b.x - mean) * rstd * g1.x + b1.x;
        o1.y = (b.y - mean) * rstd * g1.y + b1.y;
        o1.z = (b.z - mean) * rstd * g1.z + b1.z;
        o1.w = (b.w - mean) * rstd * g1.w + b1.w;
    } else {
        o0 = a; o1 = b;
    }
    bf16* xo = xn + (size_t)t * 512 + lane * 8;
    bf16x4_t p0, p1;
    p0[0] = (bf16)o0.x; p0[1] = (bf16)o0.y; p0[2] = (bf16)o0.z; p0[3] = (bf16)o0.w;
    p1[0] = (bf16)o1.x; p1[1] = (bf16)o1.y; p1[2] = (bf16)o1.z; p1[3] = (bf16)o1.w;
    *(bf16x4_t*)xo = p0;
    *(bf16x4_t*)(xo + 4) = p1;
}

// ---------------- QKV GEMM + fused V transpose ----------------
// blocks by<8: q/k epilogue [BH,S,64]; by>=8: V tile transposed in-LDS, vt [BH,64,S] coalesced
__global__ __launch_bounds__(256) void gemmqkv_k(const bf16* __restrict__ A,
                                                 const bf16* __restrict__ B,
                                                 const float* __restrict__ bias,
                                                 bf16* __restrict__ q,
                                                 bf16* __restrict__ kk,
                                                 bf16* __restrict__ vt) {
    int m0 = blockIdx.x * 128, n0 = blockIdx.y * 128;
    int tid = threadIdx.x;
    int lane = tid & 63, w = tid >> 6;
    int quad = lane >> 4, l15 = lane & 15;
    int wm = (w >> 1) * 64, wn = (w & 1) * 64;
    __shared__ bf16 smem[128 * 144]; // As | Bs, reused as Ts (128x136) for V transpose
    bf16* As = smem;
    bf16* Bs = smem + 128 * 72;
    f32x4_t acc[4][4] = {};
    int srow = tid >> 3, ssub = tid & 7;
    const bf16* Ab = A + (size_t)(m0 + srow) * 512 + ssub * 8;
    const bf16* Bb = B + (size_t)(n0 + srow) * 512 + ssub * 8;
    uint4 pa[4], pb[4];
    auto gload = [&](int s) {
        int k0 = s * 64;
#pragma unroll
        for (int i = 0; i < 4; ++i) {
            pa[i] = *(const uint4*)(Ab + (size_t)(i * 32) * 512 + k0);
            pb[i] = *(const uint4*)(Bb + (size_t)(i * 32) * 512 + k0);
        }
    };
    auto sstore = [&]() {
#pragma unroll
        for (int i = 0; i < 4; ++i) {
            *(uint4*)&As[(i * 32 + srow) * 72 + ssub * 8] = pa[i];
            *(uint4*)&Bs[(i * 32 + srow) * 72 + ssub * 8] = pb[i];
        }
    };
    gload(0);
    sstore();
    for (int s = 0; s < 8; ++s) {
        __syncthreads();
        if (s < 7) gload(s + 1);
#pragma unroll
        for (int ks = 0; ks < 2; ++ks) {
            bf16x8_t af[4], bfr[4];
            int koff = ks * 32 + quad * 8;
#pragma unroll
            for (int mt = 0; mt < 4; ++mt)
                af[mt] = *(const bf16x8_t*)&As[(wm + mt * 16 + l15) * 72 + koff];
#pragma unroll
            for (int nt = 0; nt < 4; ++nt)
                bfr[nt] = *(const bf16x8_t*)&Bs[(wn + nt * 16 + l15) * 72 + koff];
#pragma unroll
            for (int mt = 0; mt < 4; ++mt)
#pragma unroll
                for (int nt = 0; nt < 4; ++nt)
                    acc[mt][nt] = MFMA16(af[mt], bfr[nt], acc[mt][nt]);
        }
        __syncthreads();
        if (s < 7) sstore();
    }
    if (blockIdx.y < 8) {
        // q / k epilogue (gcol < 1024)
#pragma unroll
        for (int mt = 0; mt < 4; ++mt) {
#pragma unroll
            for (int nt = 0; nt < 4; ++nt) {
                int gcol = n0 + wn + nt * 16 + l15;
                float bcol = bias[gcol];
#pragma unroll
                for (int r = 0; r < 4; ++r) {
                    int grow = m0 + wm + mt * 16 + quad * 4 + r;
                    float v = acc[mt][nt][r] + bcol;
                    int d = gcol & 511;
                    int hh = d >> 6, hd = d & 63;
                    int b = grow >> 11, ssi = grow & 2047;
                    size_t idx = (((size_t)(b * 8 + hh)) * 2048 + ssi) * 64 + hd;
                    if (gcol < 512) q[idx] = (bf16)(v * 0.180336880111f); // 0.125*log2(e)
                    else kk[idx] = (bf16)v;
                }
            }
        }
    } else {
        // V tile: stage to Ts[token][d] (stride 136), then write vt coalesced along S
        __syncthreads(); // all waves done reading As/Bs
#pragma unroll
        for (int mt = 0; mt < 4; ++mt)
#pragma unroll
            for (int nt = 0; nt < 4; ++nt) {
                int gcol = n0 + wn + nt * 16 + l15;
                float bcol = bias[gcol];
#pragma unroll
                for (int r = 0; r < 4; ++r) {
                    int tok = wm + mt * 16 + quad * 4 + r;
                    smem[tok * 136 + wn + nt * 16 + l15] = (bf16)(acc[mt][nt][r] + bcol);
                }
            }
        __syncthreads();
        int dl = tid >> 1, seg = tid & 1; // d-local 0..127, token half
        int d = (n0 - 1024) + dl;
        int hh = d >> 6, hd = d & 63;
        int b = m0 >> 11, ssi0 = m0 & 2047;
        bf16* dst = vt + ((size_t)(b * 8 + hh) * 64 + hd) * 2048 + ssi0 + seg * 64;
#pragma unroll
        for (int u = 0; u < 8; ++u) {
            bf16 tmp[8];
#pragma unroll
            for (int j = 0; j < 8; ++j) tmp[j] = smem[(seg * 64 + u * 8 + j) * 136 + dl];
            *(uint4*)(dst + u * 8) = *(uint4*)tmp;
        }
    }
}

// ---------------- flash attention: 64 q-rows/block (occupancy), R8-proven compute, nsplit=4 ----------------
// q,k: [BH,S,64] (q pre-scaled by 0.125*log2e); vt: [BH,64,S]
// pO: [4][BH,S,64] bf16 un-normalized; pL: [4][BH,S] f32 row sums
// LDS 27.6 KB -> 5 blocks/CU (vs 36.9 KB -> 4); per-wave tile 16q x 64kv
__global__ __launch_bounds__(256) void attn_k(const bf16* __restrict__ q,
                                              const bf16* __restrict__ k,
                                              const bf16* __restrict__ vt,
                                              bf16* __restrict__ pO,
                                              float* __restrict__ pL) {
    int bh = blockIdx.y;
    int q0 = blockIdx.x * 64;
    int sz = blockIdx.z;
    int tid = threadIdx.x;
    int lane = tid & 63, w = tid >> 6;
    int quad = lane >> 4, l15 = lane & 15;
    __shared__ bf16 Ks[64 * 72];
    __shared__ bf16 Vs[64 * 72];
    __shared__ bf16 Ps[64 * 72];
    const bf16* qb = q + (size_t)bh * 2048 * 64;
    const bf16* kb = k + (size_t)bh * 2048 * 64;
    const bf16* vb = vt + (size_t)bh * 64 * 2048;
    bf16x8_t qf[2]; // A-operand: m=q(l15), k=d(ks*32+quad*8+j); wave rows [w*16, w*16+16)
#pragma unroll
    for (int ks = 0; ks < 2; ++ks)
        qf[ks] = *(const bf16x8_t*)(qb + (size_t)(q0 + w * 16 + l15) * 64 + ks * 32 + quad * 8);
    bf16x8_t ones8;
#pragma unroll
    for (int i = 0; i < 8; ++i) ones8[i] = (bf16)1.0f;
    f32x4_t oacc[4] = {};
    f32x4_t lacc = {};
    int srow = tid >> 3, ssub = tid & 7;
    for (int kt = sz * 8; kt < sz * 8 + 8; ++kt) {
        int kbase = kt * 64;
        __syncthreads();
#pragma unroll
        for (int i = 0; i < 2; ++i) {
            int row = i * 32 + srow;
            *(uint4*)&Ks[row * 72 + ssub * 8] = *(const uint4*)(kb + (size_t)(kbase + row) * 64 + ssub * 8);
            *(uint4*)&Vs[row * 72 + ssub * 8] = *(const uint4*)(vb + (size_t)row * 2048 + kbase + ssub * 8);
        }
        __syncthreads();
        // S = Q K^T (log2-domain scale folded into q); C: row=q(quad*4+r), col=kv(l15)
        f32x4_t sacc[4] = {};
#pragma unroll
        for (int ks = 0; ks < 2; ++ks) {
            bf16x8_t kf[4];
            int koff = ks * 32 + quad * 8;
#pragma unroll
            for (int nt = 0; nt < 4; ++nt) kf[nt] = *(const bf16x8_t*)&Ks[(nt * 16 + l15) * 72 + koff];
#pragma unroll
            for (int nt = 0; nt < 4; ++nt)
                sacc[nt] = MFMA16(qf[ks], kf[nt], sacc[nt]);
        }
        // P = exp2(S) -> Ps[q][kv] in A-operand layout (wave-private rows)
#pragma unroll
        for (int nt = 0; nt < 4; ++nt)
#pragma unroll
            for (int r = 0; r < 4; ++r)
                Ps[(w * 16 + quad * 4 + r) * 72 + nt * 16 + l15] = (bf16)exp2f(sacc[nt][r]);
        // O += P V ; l += P . 1
#pragma unroll
        for (int ks = 0; ks < 2; ++ks) {
            int koff = ks * 32 + quad * 8;
            bf16x8_t pf, vf[4];
            pf = *(const bf16x8_t*)&Ps[(w * 16 + l15) * 72 + koff];
#pragma unroll
            for (int nt = 0; nt < 4; ++nt) vf[nt] = *(const bf16x8_t*)&Vs[(nt * 16 + l15) * 72 + koff];
#pragma unroll
            for (int nt = 0; nt < 4; ++nt)
                oacc[nt] = MFMA16(pf, vf[nt], oacc[nt]);
            lacc = MFMA16(pf, ones8, lacc);
        }
    }
    size_t obase = ((size_t)(sz * 32 + bh) * 2048 + q0);
#pragma unroll
    for (int r = 0; r < 4; ++r) {
        int row = w * 16 + quad * 4 + r;
#pragma unroll
        for (int nt = 0; nt < 4; ++nt)
            pO[(obase + row) * 64 + nt * 16 + l15] = (bf16)oacc[nt][r];
        if (l15 == 0) pL[obase + row] = lacc[r];
    }
}

// ---------------- out-proj GEMM with fused split-combine A-staging (NSPLIT=4) ----------------
__global__ __launch_bounds__(256) void gemmo_k(const bf16* __restrict__ pO,
                                               const float* __restrict__ pL,
                                               const bf16* __restrict__ B,
                                               const float* __restrict__ bias,
                                               const bf16* __restrict__ xn,
                                               float* __restrict__ xrf) {
    int m0 = blockIdx.x * 128, n0 = blockIdx.y * 128;
    int tid = threadIdx.x;
    int lane = tid & 63, w = tid >> 6;
    int quad = lane >> 4, l15 = lane & 15;
    int wm = (w >> 1) * 64, wn = (w & 1) * 64;
    __shared__ bf16 As[128 * 72];
    __shared__ bf16 Bs[128 * 72];
    f32x4_t acc[4][4] = {};
    int srow = tid >> 3, ssub = tid & 7;
    const bf16* Bb = B + (size_t)(n0 + srow) * 512 + ssub * 8;
    bf16x8_t pa[4];
    uint4 pb[4];
    auto gload = [&](int s) {
        int k0 = s * 64;
#pragma unroll
        for (int i = 0; i < 4; ++i) {
            int t = m0 + i * 32 + srow;
            int b = t >> 11, ssi = t & 2047;
            float lsum = 0.f;
            float facc[8] = {};
#pragma unroll
            for (int sp = 0; sp < 4; ++sp) {
                size_t r = ((size_t)(sp * 32 + b * 8 + s)) * 2048 + ssi;
                lsum += pL[r];
                bf16x8_t av = *(const bf16x8_t*)(pO + r * 64 + ssub * 8);
#pragma unroll
                for (int j = 0; j < 8; ++j) facc[j] += (float)av[j];
            }
            float inv = 1.f / lsum;
            bf16x8_t c;
#pragma unroll
            for (int j = 0; j < 8; ++j) c[j] = (bf16)(facc[j] * inv);
            pa[i] = c;
            pb[i] = *(const uint4*)(Bb + (size_t)(i * 32) * 512 + k0);
        }
    };
    auto sstore = [&]() {
#pragma unroll
        for (int i = 0; i < 4; ++i) {
            *(bf16x8_t*)&As[(i * 32 + srow) * 72 + ssub * 8] = pa[i];
            *(uint4*)&Bs[(i * 32 + srow) * 72 + ssub * 8] = pb[i];
        }
    };
    gload(0);
    sstore();
    for (int s = 0; s < 8; ++s) {
        __syncthreads();
        if (s < 7) gload(s + 1);
#pragma unroll
        for (int ks = 0; ks < 2; ++ks) {
            bf16x8_t af[4], bfr[4];
            int koff = ks * 32 + quad * 8;
#pragma unroll
            for (int mt = 0; mt < 4; ++mt)
                af[mt] = *(const bf16x8_t*)&As[(wm + mt * 16 + l15) * 72 + koff];
#pragma unroll
            for (int nt = 0; nt < 4; ++nt)
                bfr[nt] = *(const bf16x8_t*)&Bs[(wn + nt * 16 + l15) * 72 + koff];
#pragma unroll
            for (int mt = 0; mt < 4; ++mt)
#pragma unroll
                for (int nt = 0; nt < 4; ++nt)
                    acc[mt][nt] = MFMA16(af[mt], bfr[nt], acc[mt][nt]);
        }
        __syncthreads();
        if (s < 7) sstore();
    }
#pragma unroll
    for (int mt = 0; mt < 4; ++mt) {
#pragma unroll
        for (int nt = 0; nt < 4; ++nt) {
            int gcol = n0 + wn + nt * 16 + l15;
            float bcol = bias[gcol];
#pragma unroll
            for (int r = 0; r < 4; ++r) {
                int grow = m0 + wm + mt * 16 + quad * 4 + r;
                size_t idx = (size_t)grow * 512 + gcol;
                xrf[idx] = acc[mt][nt][r] + bcol + (float)xn[idx];
            }
        }
    }
}

// ---------------- fused MLP gate: h = silu(xrf*w1^T+b1); st = sigmoid(h.w2+b2); out = xrf*st ----------------
__global__ __launch_bounds__(256) void mlp_k(const bf16* __restrict__ B,   // w1b [256,512]
                                             const float* __restrict__ b1,
                                             const float* __restrict__ w2,
                                             const float* __restrict__ b2,
                                             const float* __restrict__ xrf,
                                             float* __restrict__ out) {
    int m0 = blockIdx.x * 32;
    int tid = threadIdx.x;
    int lane = tid & 63, w = tid >> 6;
    int quad = lane >> 4, l15 = lane & 15;
    int wn = w * 64;
    __shared__ bf16 As[32 * 72];
    __shared__ bf16 Bs[256 * 72];
    __shared__ float red[4][32];
    __shared__ float st[32];
    f32x4_t acc[2][4] = {};
    int srow = tid >> 3, ssub = tid & 7;
    bf16x8_t pa;
    uint4 pb[8];
    auto gload = [&](int s) {
        int k0 = s * 64;
        const float* ar = xrf + (size_t)(m0 + srow) * 512 + ssub * 8 + k0;
        float4 f0 = *(const float4*)ar;
        float4 f1 = *(const float4*)(ar + 4);
        pa[0] = (bf16)f0.x; pa[1] = (bf16)f0.y; pa[2] = (bf16)f0.z; pa[3] = (bf16)f0.w;
        pa[4] = (bf16)f1.x; pa[5] = (bf16)f1.y; pa[6] = (bf16)f1.z; pa[7] = (bf16)f1.w;
#pragma unroll
        for (int i = 0; i < 8; ++i)
            pb[i] = *(const uint4*)(B + (size_t)(i * 32 + srow) * 512 + ssub * 8 + k0);
    };
    auto sstore = [&]() {
        *(bf16x8_t*)&As[srow * 72 + ssub * 8] = pa;
#pragma unroll
        for (int i = 0; i < 8; ++i)
            *(uint4*)&Bs[(i * 32 + srow) * 72 + ssub * 8] = pb[i];
    };
    gload(0);
    sstore();
    for (int s = 0; s < 8; ++s) {
        __syncthreads();
        if (s < 7) gload(s + 1);
#pragma unroll
        for (int ks = 0; ks < 2; ++ks) {
            int koff = ks * 32 + quad * 8;
            bf16x8_t af[2], bfr[4];
#pragma unroll
            for (int mt = 0; mt < 2; ++mt)
                af[mt] = *(const bf16x8_t*)&As[(mt * 16 + l15) * 72 + koff];
#pragma unroll
            for (int nt = 0; nt < 4; ++nt)
                bfr[nt] = *(const bf16x8_t*)&Bs[(wn + nt * 16 + l15) * 72 + koff];
#pragma unroll
            for (int mt = 0; mt < 2; ++mt)
#pragma unroll
                for (int nt = 0; nt < 4; ++nt)
                    acc[mt][nt] = MFMA16(af[mt], bfr[nt], acc[mt][nt]);
        }
        __syncthreads();
        if (s < 7) sstore();
    }
    f32x4_t ds[2] = {};
#pragma unroll
    for (int mt = 0; mt < 2; ++mt)
#pragma unroll
        for (int nt = 0; nt < 4; ++nt) {
            int gcol = wn + nt * 16 + l15;
            float bb = b1[gcol], ww = w2[gcol];
#pragma unroll
            for (int r = 0; r < 4; ++r) {
                float v = acc[mt][nt][r] + bb;
                float sv = v / (1.f + __expf(-v));
                ds[mt][r] += sv * ww;
            }
        }
#pragma unroll
    for (int m = 1; m < 16; m <<= 1)
#pragma unroll
        for (int mt = 0; mt < 2; ++mt)
#pragma unroll
            for (int r = 0; r < 4; ++r) ds[mt][r] += __shfl_xor(ds[mt][r], m, 64);
    if (l15 == 0) {
#pragma unroll
        for (int mt = 0; mt < 2; ++mt)
#pragma unroll
            for (int r = 0; r < 4; ++r) red[w][mt * 16 + quad * 4 + r] = ds[mt][r];
    }
    __syncthreads();
    if (tid < 32) {
        float d = red[0][tid] + red[1][tid] + red[2][tid] + red[3][tid] + b2[0];
        st[tid] = 1.f / (1.f + __expf(-d));
    }
    __syncthreads();
    int row = tid >> 3, seg = tid & 7;
    float sr = st[row];
    const float4* x4 = (const float4*)(xrf + (size_t)(m0 + row) * 512);
    float4* o4 = (float4*)(out + (size_t)(m0 + row) * 512);
#pragma unroll
    for (int jj = 0; jj < 16; ++jj) {
        float4 xv = x4[jj * 8 + seg];
        float4 ov;
        ov.x = xv.x * sr; ov.y = xv.y * sr; ov.z = xv.z * sr; ov.w = xv.w * sr;
        o4[jj * 8 + seg] = ov;
    }
}

extern "C" void kernel_launch(void* const* d_in, const int* in_sizes, int n_in,
                              void* d_out, int out_size, void* d_ws, size_t ws_size,
                              hipStream_t stream) {
    const float* x    = (const float*)d_in[0];
    const int*   gt   = (const int*)d_in[1];
    const float* tfg  = (const float*)d_in[2];
    const float* tfb  = (const float*)d_in[3];
    const float* tgg  = (const float*)d_in[4];
    const float* tgb  = (const float*)d_in[5];
    const float* Wqkv = (const float*)d_in[6];
    const float* bqkv = (const float*)d_in[7];
    const float* Wout = (const float*)d_in[8];
    const float* bout = (const float*)d_in[9];
    const float* W1   = (const float*)d_in[10];
    const float* b1   = (const float*)d_in[11];
    const float* w2   = (const float*)d_in[12];
    const float* b2   = (const float*)d_in[13];
    float* out = (float*)d_out;
    char* ws = (char*)d_ws;

    const size_t MB = 1024 * 1024;
    // [0,4MB): weights + row sums
    bf16*  wq  = (bf16*)(ws + 0);                          // 1.5 MB [1536,512]
    bf16*  wo  = (bf16*)(ws + 1536 * 512 * 2);             // 0.5 MB [512,512]
    bf16*  w1b = (bf16*)(ws + (1536 + 512) * 512 * 2);     // 0.25 MB [256,512]
    float* pL  = (float*)(ws + 2304 * 512 * 2);            // 1 MB [4][32,2048]
    // activations (aliased by liveness); peak 68 MB (nsplit=4 proven to fit in R4/R8)
    bf16*  xn  = (bf16*)(ws + 4 * MB);   //  8 MB [8192,512]          live: castln..gemmo
    bf16*  q   = (bf16*)(ws + 12 * MB);  //  8 MB [32,2048,64]        live: gemmqkv..attn
    bf16*  kk  = (bf16*)(ws + 20 * MB);  //  8 MB [32,2048,64]        live: gemmqkv..attn
    float* xrf = (float*)(ws + 12 * MB); // 16 MB [8192,512] (=q,kk)  live: gemmo..mlp
    bf16*  vt  = (bf16*)(ws + 28 * MB);  //  8 MB [32,64,2048]        live: gemmqkv..attn
    bf16*  pO  = (bf16*)(ws + 36 * MB);  // 32 MB [4][32,2048,64]     live: attn..gemmo

    castln_k<<<6656, 256, 0, stream>>>(Wqkv, Wout, W1, wq, wo, w1b,
                                       x, gt, tfg, tfb, tgg, tgb, xn);
    gemmqkv_k<<<dim3(64, 12), 256, 0, stream>>>(xn, wq, bqkv, q, kk, vt);
    attn_k<<<dim3(32, 32, 4), 256, 0, stream>>>(q, kk, vt, pO, pL);
    gemmo_k<<<dim3(64, 4), 256, 0, stream>>>(pO, pL, wo, bout, xn, xrf);
    mlp_k<<<256, 256, 0, stream>>>(w1b, b1, w2, b2, xrf, out);
    (void)in_sizes; (void)n_in; (void)out_size; (void)ws_size;
}

// Round 10
// 317.101 us; speedup vs baseline: 1.0059x; 1.0059x over previous
//
#include <hip/hip_runtime.h>

typedef __bf16 bf16;
typedef __bf16 bf16x4_t __attribute__((ext_vector_type(4)));
typedef __bf16 bf16x8_t __attribute__((ext_vector_type(8)));
typedef float f32x4_t __attribute__((ext_vector_type(4)));

#define MFMA16(a, b, c) __builtin_amdgcn_mfma_f32_16x16x32_bf16(a, b, c, 0, 0, 0)

// ---------------- fused: weight casts (blocks 0..4607) + conditional LN (4608..6655) ----------------
__global__ __launch_bounds__(256) void castln_k(const float* __restrict__ Wqkv,
                                                const float* __restrict__ Wout,
                                                const float* __restrict__ W1,
                                                bf16* __restrict__ wq,
                                                bf16* __restrict__ wo,
                                                bf16* __restrict__ w1b,
                                                const float* __restrict__ x,
                                                const int* __restrict__ gt,
                                                const float* __restrict__ tfg,
                                                const float* __restrict__ tfb,
                                                const float* __restrict__ tgg,
                                                const float* __restrict__ tgb,
                                                bf16* __restrict__ xn) {
    if (blockIdx.x < 4608) {
        int i = blockIdx.x * 256 + threadIdx.x;
        if (i < 786432) wq[i] = (bf16)Wqkv[i];
        else if (i < 1048576) wo[i - 786432] = (bf16)Wout[i - 786432];
        else if (i < 1179648) w1b[i - 1048576] = (bf16)W1[i - 1048576];
        return;
    }
    int wid = threadIdx.x >> 6, lane = threadIdx.x & 63;
    int t = (blockIdx.x - 4608) * 4 + wid;
    const float4* xr = (const float4*)(x + (size_t)t * 512);
    float4 a = xr[lane * 2], b = xr[lane * 2 + 1];
    float s = (a.x + a.y) + (a.z + a.w) + (b.x + b.y) + (b.z + b.w);
    float sq = a.x * a.x + a.y * a.y + a.z * a.z + a.w * a.w +
               b.x * b.x + b.y * b.y + b.z * b.z + b.w * b.w;
    for (int m = 1; m < 64; m <<= 1) {
        s += __shfl_xor(s, m, 64);
        sq += __shfl_xor(sq, m, 64);
    }
    float mean = s * (1.f / 512.f);
    float var = fmaxf(sq * (1.f / 512.f) - mean * mean, 0.f);
    float rstd = rsqrtf(var + 1e-5f);
    int g = gt[t];
    float4 o0, o1;
    if (g < 2) {
        const float4* gp = (const float4*)(g ? tgg : tfg);
        const float4* bp = (const float4*)(g ? tgb : tfb);
        float4 g0 = gp[lane * 2], g1 = gp[lane * 2 + 1];
        float4 b0 = bp[lane * 2], b1 = bp[lane * 2 + 1];
        o0.x = (a.x - mean) * rstd * g0.x + b0.x;
        o0.y = (a.y - mean) * rstd * g0.y + b0.y;
        o0.z = (a.z - mean) * rstd * g0.z + b0.z;
        o0.w = (a.w - mean) * rstd * g0.w + b0.w;
        o1.x = (b.x - mean) * rstd * g1.x + b1.x;
        o1.y = (b.y - mean) * rstd * g1.y + b1.y;
        o1.z = (b.z - mean) * rstd * g1.z + b1.z;
        o1.w = (b.w - mean) * rstd * g1.w + b1.w;
    } else {
        o0 = a; o1 = b;
    }
    bf16* xo = xn + (size_t)t * 512 + lane * 8;
    bf16x4_t p0, p1;
    p0[0] = (bf16)o0.x; p0[1] = (bf16)o0.y; p0[2] = (bf16)o0.z; p0[3] = (bf16)o0.w;
    p1[0] = (bf16)o1.x; p1[1] = (bf16)o1.y; p1[2] = (bf16)o1.z; p1[3] = (bf16)o1.w;
    *(bf16x4_t*)xo = p0;
    *(bf16x4_t*)(xo + 4) = p1;
}

// ---------------- QKV GEMM + fused V transpose ----------------
__global__ __launch_bounds__(256) void gemmqkv_k(const bf16* __restrict__ A,
                                                 const bf16* __restrict__ B,
                                                 const float* __restrict__ bias,
                                                 bf16* __restrict__ q,
                                                 bf16* __restrict__ kk,
                                                 bf16* __restrict__ vt) {
    int m0 = blockIdx.x * 128, n0 = blockIdx.y * 128;
    int tid = threadIdx.x;
    int lane = tid & 63, w = tid >> 6;
    int quad = lane >> 4, l15 = lane & 15;
    int wm = (w >> 1) * 64, wn = (w & 1) * 64;
    __shared__ bf16 smem[128 * 144]; // As | Bs, reused as Ts (128x136) for V transpose
    bf16* As = smem;
    bf16* Bs = smem + 128 * 72;
    f32x4_t acc[4][4] = {};
    int srow = tid >> 3, ssub = tid & 7;
    const bf16* Ab = A + (size_t)(m0 + srow) * 512 + ssub * 8;
    const bf16* Bb = B + (size_t)(n0 + srow) * 512 + ssub * 8;
    uint4 pa[4], pb[4];
    auto gload = [&](int s) {
        int k0 = s * 64;
#pragma unroll
        for (int i = 0; i < 4; ++i) {
            pa[i] = *(const uint4*)(Ab + (size_t)(i * 32) * 512 + k0);
            pb[i] = *(const uint4*)(Bb + (size_t)(i * 32) * 512 + k0);
        }
    };
    auto sstore = [&]() {
#pragma unroll
        for (int i = 0; i < 4; ++i) {
            *(uint4*)&As[(i * 32 + srow) * 72 + ssub * 8] = pa[i];
            *(uint4*)&Bs[(i * 32 + srow) * 72 + ssub * 8] = pb[i];
        }
    };
    gload(0);
    sstore();
    for (int s = 0; s < 8; ++s) {
        __syncthreads();
        if (s < 7) gload(s + 1);
#pragma unroll
        for (int ks = 0; ks < 2; ++ks) {
            bf16x8_t af[4], bfr[4];
            int koff = ks * 32 + quad * 8;
#pragma unroll
            for (int mt = 0; mt < 4; ++mt)
                af[mt] = *(const bf16x8_t*)&As[(wm + mt * 16 + l15) * 72 + koff];
#pragma unroll
            for (int nt = 0; nt < 4; ++nt)
                bfr[nt] = *(const bf16x8_t*)&Bs[(wn + nt * 16 + l15) * 72 + koff];
#pragma unroll
            for (int mt = 0; mt < 4; ++mt)
#pragma unroll
                for (int nt = 0; nt < 4; ++nt)
                    acc[mt][nt] = MFMA16(af[mt], bfr[nt], acc[mt][nt]);
        }
        __syncthreads();
        if (s < 7) sstore();
    }
    if (blockIdx.y < 8) {
        // q / k epilogue (gcol < 1024)
#pragma unroll
        for (int mt = 0; mt < 4; ++mt) {
#pragma unroll
            for (int nt = 0; nt < 4; ++nt) {
                int gcol = n0 + wn + nt * 16 + l15;
                float bcol = bias[gcol];
#pragma unroll
                for (int r = 0; r < 4; ++r) {
                    int grow = m0 + wm + mt * 16 + quad * 4 + r;
                    float v = acc[mt][nt][r] + bcol;
                    int d = gcol & 511;
                    int hh = d >> 6, hd = d & 63;
                    int b = grow >> 11, ssi = grow & 2047;
                    size_t idx = (((size_t)(b * 8 + hh)) * 2048 + ssi) * 64 + hd;
                    if (gcol < 512) q[idx] = (bf16)(v * 0.180336880111f); // 0.125*log2(e)
                    else kk[idx] = (bf16)v;
                }
            }
        }
    } else {
        // V tile: stage to Ts[token][d] (stride 136), then write vt coalesced along S
        __syncthreads(); // all waves done reading As/Bs
#pragma unroll
        for (int mt = 0; mt < 4; ++mt)
#pragma unroll
            for (int nt = 0; nt < 4; ++nt) {
                int gcol = n0 + wn + nt * 16 + l15;
                float bcol = bias[gcol];
#pragma unroll
                for (int r = 0; r < 4; ++r) {
                    int tok = wm + mt * 16 + quad * 4 + r;
                    smem[tok * 136 + wn + nt * 16 + l15] = (bf16)(acc[mt][nt][r] + bcol);
                }
            }
        __syncthreads();
        int dl = tid >> 1, seg = tid & 1; // d-local 0..127, token half
        int d = (n0 - 1024) + dl;
        int hh = d >> 6, hd = d & 63;
        int b = m0 >> 11, ssi0 = m0 & 2047;
        bf16* dst = vt + ((size_t)(b * 8 + hh) * 64 + hd) * 2048 + ssi0 + seg * 64;
#pragma unroll
        for (int u = 0; u < 8; ++u) {
            bf16 tmp[8];
#pragma unroll
            for (int j = 0; j < 8; ++j) tmp[j] = smem[(seg * 64 + u * 8 + j) * 136 + dl];
            *(uint4*)(dst + u * 8) = *(uint4*)tmp;
        }
    }
}

// ---------------- flash attention: 256 q-rows/block, 64q per wave (max reuse per LDS read) ----------------
// q,k: [BH,S,64] (q pre-scaled by 0.125*log2e); vt: [BH,64,S]
// pO: [4][BH,S,64] bf16 un-normalized; pL: [4][BH,S] f32 row sums
// Per wave-tile (64q x 64kv): each kf/vf LDS read feeds 4 MFMAs (vs 2 at 128q blocks).
// sacc kept to 16 regs via nt-loop; LDS 55.3 KB -> 2 blocks/CU.
__global__ __launch_bounds__(256) void attn_k(const bf16* __restrict__ q,
                                              const bf16* __restrict__ k,
                                              const bf16* __restrict__ vt,
                                              bf16* __restrict__ pO,
                                              float* __restrict__ pL) {
    int bh = blockIdx.y;
    int q0 = blockIdx.x * 256;
    int sz = blockIdx.z;
    int tid = threadIdx.x;
    int lane = tid & 63, w = tid >> 6;
    int quad = lane >> 4, l15 = lane & 15;
    __shared__ bf16 Ks[64 * 72];
    __shared__ bf16 Vs[64 * 72];
    __shared__ bf16 Ps[256 * 72]; // wave-private 64-row slabs
    const bf16* qb = q + (size_t)bh * 2048 * 64;
    const bf16* kb = k + (size_t)bh * 2048 * 64;
    const bf16* vb = vt + (size_t)bh * 64 * 2048;
    bf16x8_t qf[4][2]; // A-operand: m=q(l15), rows w*64+mt*16+l15
#pragma unroll
    for (int mt = 0; mt < 4; ++mt)
#pragma unroll
        for (int ks = 0; ks < 2; ++ks)
            qf[mt][ks] = *(const bf16x8_t*)(qb + (size_t)(q0 + w * 64 + mt * 16 + l15) * 64 + ks * 32 + quad * 8);
    bf16x8_t ones8;
#pragma unroll
    for (int i = 0; i < 8; ++i) ones8[i] = (bf16)1.0f;
    f32x4_t oacc[4][4] = {};
    f32x4_t lacc[4] = {};
    int srow = tid >> 3, ssub = tid & 7;
    for (int kt = sz * 8; kt < sz * 8 + 8; ++kt) {
        int kbase = kt * 64;
        __syncthreads();
#pragma unroll
        for (int i = 0; i < 2; ++i) {
            int row = i * 32 + srow;
            *(uint4*)&Ks[row * 72 + ssub * 8] = *(const uint4*)(kb + (size_t)(kbase + row) * 64 + ssub * 8);
            *(uint4*)&Vs[row * 72 + ssub * 8] = *(const uint4*)(vb + (size_t)row * 2048 + kbase + ssub * 8);
        }
        __syncthreads();
        // S = Q K^T, one kv-subtile (nt) at a time: sacc live range = 16 regs
#pragma unroll
        for (int nt = 0; nt < 4; ++nt) {
            f32x4_t sacc[4] = {};
#pragma unroll
            for (int ks = 0; ks < 2; ++ks) {
                bf16x8_t kf = *(const bf16x8_t*)&Ks[(nt * 16 + l15) * 72 + ks * 32 + quad * 8];
#pragma unroll
                for (int mt = 0; mt < 4; ++mt)
                    sacc[mt] = MFMA16(qf[mt][ks], kf, sacc[mt]);
            }
            // P = exp2(S) -> Ps (A-operand layout, wave-private rows)
#pragma unroll
            for (int mt = 0; mt < 4; ++mt)
#pragma unroll
                for (int r = 0; r < 4; ++r)
                    Ps[(w * 64 + mt * 16 + quad * 4 + r) * 72 + nt * 16 + l15] = (bf16)exp2f(sacc[mt][r]);
        }
        // O += P V ; l += P . 1
#pragma unroll
        for (int ks = 0; ks < 2; ++ks) {
            int koff = ks * 32 + quad * 8;
            bf16x8_t pf[4], vf[4];
#pragma unroll
            for (int mt = 0; mt < 4; ++mt)
                pf[mt] = *(const bf16x8_t*)&Ps[(w * 64 + mt * 16 + l15) * 72 + koff];
#pragma unroll
            for (int nt = 0; nt < 4; ++nt)
                vf[nt] = *(const bf16x8_t*)&Vs[(nt * 16 + l15) * 72 + koff];
#pragma unroll
            for (int mt = 0; mt < 4; ++mt) {
#pragma unroll
                for (int nt = 0; nt < 4; ++nt)
                    oacc[mt][nt] = MFMA16(pf[mt], vf[nt], oacc[mt][nt]);
                lacc[mt] = MFMA16(pf[mt], ones8, lacc[mt]);
            }
        }
    }
    size_t obase = ((size_t)(sz * 32 + bh) * 2048 + q0);
#pragma unroll
    for (int mt = 0; mt < 4; ++mt)
#pragma unroll
        for (int r = 0; r < 4; ++r) {
            int row = w * 64 + mt * 16 + quad * 4 + r;
#pragma unroll
            for (int nt = 0; nt < 4; ++nt)
                pO[(obase + row) * 64 + nt * 16 + l15] = (bf16)oacc[mt][nt][r];
            if (l15 == 0) pL[obase + row] = lacc[mt][r];
        }
}

// ---------------- out-proj GEMM with fused split-combine A-staging (NSPLIT=4) ----------------
__global__ __launch_bounds__(256) void gemmo_k(const bf16* __restrict__ pO,
                                               const float* __restrict__ pL,
                                               const bf16* __restrict__ B,
                                               const float* __restrict__ bias,
                                               const bf16* __restrict__ xn,
                                               float* __restrict__ xrf) {
    int m0 = blockIdx.x * 128, n0 = blockIdx.y * 128;
    int tid = threadIdx.x;
    int lane = tid & 63, w = tid >> 6;
    int quad = lane >> 4, l15 = lane & 15;
    int wm = (w >> 1) * 64, wn = (w & 1) * 64;
    __shared__ bf16 As[128 * 72];
    __shared__ bf16 Bs[128 * 72];
    f32x4_t acc[4][4] = {};
    int srow = tid >> 3, ssub = tid & 7;
    const bf16* Bb = B + (size_t)(n0 + srow) * 512 + ssub * 8;
    bf16x8_t pa[4];
    uint4 pb[4];
    auto gload = [&](int s) {
        int k0 = s * 64;
#pragma unroll
        for (int i = 0; i < 4; ++i) {
            int t = m0 + i * 32 + srow;
            int b = t >> 11, ssi = t & 2047;
            float lsum = 0.f;
            float facc[8] = {};
#pragma unroll
            for (int sp = 0; sp < 4; ++sp) {
                size_t r = ((size_t)(sp * 32 + b * 8 + s)) * 2048 + ssi;
                lsum += pL[r];
                bf16x8_t av = *(const bf16x8_t*)(pO + r * 64 + ssub * 8);
#pragma unroll
                for (int j = 0; j < 8; ++j) facc[j] += (float)av[j];
            }
            float inv = 1.f / lsum;
            bf16x8_t c;
#pragma unroll
            for (int j = 0; j < 8; ++j) c[j] = (bf16)(facc[j] * inv);
            pa[i] = c;
            pb[i] = *(const uint4*)(Bb + (size_t)(i * 32) * 512 + k0);
        }
    };
    auto sstore = [&]() {
#pragma unroll
        for (int i = 0; i < 4; ++i) {
            *(bf16x8_t*)&As[(i * 32 + srow) * 72 + ssub * 8] = pa[i];
            *(uint4*)&Bs[(i * 32 + srow) * 72 + ssub * 8] = pb[i];
        }
    };
    gload(0);
    sstore();
    for (int s = 0; s < 8; ++s) {
        __syncthreads();
        if (s < 7) gload(s + 1);
#pragma unroll
        for (int ks = 0; ks < 2; ++ks) {
            bf16x8_t af[4], bfr[4];
            int koff = ks * 32 + quad * 8;
#pragma unroll
            for (int mt = 0; mt < 4; ++mt)
                af[mt] = *(const bf16x8_t*)&As[(wm + mt * 16 + l15) * 72 + koff];
#pragma unroll
            for (int nt = 0; nt < 4; ++nt)
                bfr[nt] = *(const bf16x8_t*)&Bs[(wn + nt * 16 + l15) * 72 + koff];
#pragma unroll
            for (int mt = 0; mt < 4; ++mt)
#pragma unroll
                for (int nt = 0; nt < 4; ++nt)
                    acc[mt][nt] = MFMA16(af[mt], bfr[nt], acc[mt][nt]);
        }
        __syncthreads();
        if (s < 7) sstore();
    }
#pragma unroll
    for (int mt = 0; mt < 4; ++mt) {
#pragma unroll
        for (int nt = 0; nt < 4; ++nt) {
            int gcol = n0 + wn + nt * 16 + l15;
            float bcol = bias[gcol];
#pragma unroll
            for (int r = 0; r < 4; ++r) {
                int grow = m0 + wm + mt * 16 + quad * 4 + r;
                size_t idx = (size_t)grow * 512 + gcol;
                xrf[idx] = acc[mt][nt][r] + bcol + (float)xn[idx];
            }
        }
    }
}

// ---------------- fused MLP gate: h = silu(xrf*w1^T+b1); st = sigmoid(h.w2+b2); out = xrf*st ----------------
__global__ __launch_bounds__(256) void mlp_k(const bf16* __restrict__ B,   // w1b [256,512]
                                             const float* __restrict__ b1,
                                             const float* __restrict__ w2,
                                             const float* __restrict__ b2,
                                             const float* __restrict__ xrf,
                                             float* __restrict__ out) {
    int m0 = blockIdx.x * 32;
    int tid = threadIdx.x;
    int lane = tid & 63, w = tid >> 6;
    int quad = lane >> 4, l15 = lane & 15;
    int wn = w * 64;
    __shared__ bf16 As[32 * 72];
    __shared__ bf16 Bs[256 * 72];
    __shared__ float red[4][32];
    __shared__ float st[32];
    f32x4_t acc[2][4] = {};
    int srow = tid >> 3, ssub = tid & 7;
    bf16x8_t pa;
    uint4 pb[8];
    auto gload = [&](int s) {
        int k0 = s * 64;
        const float* ar = xrf + (size_t)(m0 + srow) * 512 + ssub * 8 + k0;
        float4 f0 = *(const float4*)ar;
        float4 f1 = *(const float4*)(ar + 4);
        pa[0] = (bf16)f0.x; pa[1] = (bf16)f0.y; pa[2] = (bf16)f0.z; pa[3] = (bf16)f0.w;
        pa[4] = (bf16)f1.x; pa[5] = (bf16)f1.y; pa[6] = (bf16)f1.z; pa[7] = (bf16)f1.w;
#pragma unroll
        for (int i = 0; i < 8; ++i)
            pb[i] = *(const uint4*)(B + (size_t)(i * 32 + srow) * 512 + ssub * 8 + k0);
    };
    auto sstore = [&]() {
        *(bf16x8_t*)&As[srow * 72 + ssub * 8] = pa;
#pragma unroll
        for (int i = 0; i < 8; ++i)
            *(uint4*)&Bs[(i * 32 + srow) * 72 + ssub * 8] = pb[i];
    };
    gload(0);
    sstore();
    for (int s = 0; s < 8; ++s) {
        __syncthreads();
        if (s < 7) gload(s + 1);
#pragma unroll
        for (int ks = 0; ks < 2; ++ks) {
            int koff = ks * 32 + quad * 8;
            bf16x8_t af[2], bfr[4];
#pragma unroll
            for (int mt = 0; mt < 2; ++mt)
                af[mt] = *(const bf16x8_t*)&As[(mt * 16 + l15) * 72 + koff];
#pragma unroll
            for (int nt = 0; nt < 4; ++nt)
                bfr[nt] = *(const bf16x8_t*)&Bs[(wn + nt * 16 + l15) * 72 + koff];
#pragma unroll
            for (int mt = 0; mt < 2; ++mt)
#pragma unroll
                for (int nt = 0; nt < 4; ++nt)
                    acc[mt][nt] = MFMA16(af[mt], bfr[nt], acc[mt][nt]);
        }
        __syncthreads();
        if (s < 7) sstore();
    }
    f32x4_t ds[2] = {};
#pragma unroll
    for (int mt = 0; mt < 2; ++mt)
#pragma unroll
        for (int nt = 0; nt < 4; ++nt) {
            int gcol = wn + nt * 16 + l15;
            float bb = b1[gcol], ww = w2[gcol];
#pragma unroll
            for (int r = 0; r < 4; ++r) {
                float v = acc[mt][nt][r] + bb;
                float sv = v / (1.f + __expf(-v));
                ds[mt][r] += sv * ww;
            }
        }
#pragma unroll
    for (int m = 1; m < 16; m <<= 1)
#pragma unroll
        for (int mt = 0; mt < 2; ++mt)
#pragma unroll
            for (int r = 0; r < 4; ++r) ds[mt][r] += __shfl_xor(ds[mt][r], m, 64);
    if (l15 == 0) {
#pragma unroll
        for (int mt = 0; mt < 2; ++mt)
#pragma unroll
            for (int r = 0; r < 4; ++r) red[w][mt * 16 + quad * 4 + r] = ds[mt][r];
    }
    __syncthreads();
    if (tid < 32) {
        float d = red[0][tid] + red[1][tid] + red[2][tid] + red[3][tid] + b2[0];
        st[tid] = 1.f / (1.f + __expf(-d));
    }
    __syncthreads();
    int row = tid >> 3, seg = tid & 7;
    float sr = st[row];
    const float4* x4 = (const float4*)(xrf + (size_t)(m0 + row) * 512);
    float4* o4 = (float4*)(out + (size_t)(m0 + row) * 512);
#pragma unroll
    for (int jj = 0; jj < 16; ++jj) {
        float4 xv = x4[jj * 8 + seg];
        float4 ov;
        ov.x = xv.x * sr; ov.y = xv.y * sr; ov.z = xv.z * sr; ov.w = xv.w * sr;
        o4[jj * 8 + seg] = ov;
    }
}

extern "C" void kernel_launch(void* const* d_in, const int* in_sizes, int n_in,
                              void* d_out, int out_size, void* d_ws, size_t ws_size,
                              hipStream_t stream) {
    const float* x    = (const float*)d_in[0];
    const int*   gt   = (const int*)d_in[1];
    const float* tfg  = (const float*)d_in[2];
    const float* tfb  = (const float*)d_in[3];
    const float* tgg  = (const float*)d_in[4];
    const float* tgb  = (const float*)d_in[5];
    const float* Wqkv = (const float*)d_in[6];
    const float* bqkv = (const float*)d_in[7];
    const float* Wout = (const float*)d_in[8];
    const float* bout = (const float*)d_in[9];
    const float* W1   = (const float*)d_in[10];
    const float* b1   = (const float*)d_in[11];
    const float* w2   = (const float*)d_in[12];
    const float* b2   = (const float*)d_in[13];
    float* out = (float*)d_out;
    char* ws = (char*)d_ws;

    const size_t MB = 1024 * 1024;
    // [0,4MB): weights + row sums
    bf16*  wq  = (bf16*)(ws + 0);                          // 1.5 MB [1536,512]
    bf16*  wo  = (bf16*)(ws + 1536 * 512 * 2);             // 0.5 MB [512,512]
    bf16*  w1b = (bf16*)(ws + (1536 + 512) * 512 * 2);     // 0.25 MB [256,512]
    float* pL  = (float*)(ws + 2304 * 512 * 2);            // 1 MB [4][32,2048]
    // activations (aliased by liveness); peak 68 MB (proven to fit, R4/R8)
    bf16*  xn  = (bf16*)(ws + 4 * MB);   //  8 MB [8192,512]          live: castln..gemmo
    bf16*  q   = (bf16*)(ws + 12 * MB);  //  8 MB [32,2048,64]        live: gemmqkv..attn
    bf16*  kk  = (bf16*)(ws + 20 * MB);  //  8 MB [32,2048,64]        live: gemmqkv..attn
    float* xrf = (float*)(ws + 12 * MB); // 16 MB [8192,512] (=q,kk)  live: gemmo..mlp
    bf16*  vt  = (bf16*)(ws + 28 * MB);  //  8 MB [32,64,2048]        live: gemmqkv..attn
    bf16*  pO  = (bf16*)(ws + 36 * MB);  // 32 MB [4][32,2048,64]     live: attn..gemmo

    castln_k<<<6656, 256, 0, stream>>>(Wqkv, Wout, W1, wq, wo, w1b,
                                       x, gt, tfg, tfb, tgg, tgb, xn);
    gemmqkv_k<<<dim3(64, 12), 256, 0, stream>>>(xn, wq, bqkv, q, kk, vt);
    attn_k<<<dim3(8, 32, 4), 256, 0, stream>>>(q, kk, vt, pO, pL);
    gemmo_k<<<dim3(64, 4), 256, 0, stream>>>(pO, pL, wo, bout, xn, xrf);
    mlp_k<<<256, 256, 0, stream>>>(w1b, b1, w2, b2, xrf, out);
    (void)in_sizes; (void)n_in; (void)out_size; (void)ws_size;
}